// Round 1
// baseline (1074.093 us; speedup 1.0000x reference)
//
#include <hip/hip_runtime.h>
#include <hip/hip_bf16.h>

#define BB   4
#define HH   128
#define WW   128
#define CC   32
#define OH   120
#define OW   120
#define KT   25
#define GG   2
#define FF   64
#define OFFC 100   // K*2*G

// ---------------------------------------------------------------------------
// Kernel 1: dilated 5x5 offset conv (VALID, dil=2), Cin=32 -> Cout=100.
// Tile: 8x8 output pixels per block, 256 threads. Input patch 16x16x32 in LDS.
// Work item = (pixel, oc-quad): w_off reads are float4, coalesced over oc.
// ---------------------------------------------------------------------------
__global__ __launch_bounds__(256) void offsets_kernel(
    const float* __restrict__ volume, const float* __restrict__ w_off,
    const float* __restrict__ b_off, float* __restrict__ offs)
{
    __shared__ float patch[16 * 16 * 32];   // 32 KB
    const int bx = blockIdx.x * 8;
    const int by = blockIdx.y * 8;
    const int b  = blockIdx.z;
    const int tid = threadIdx.x;

    const float* vbase = volume + (size_t)b * HH * WW * CC;
    // stage input region y in [by, by+16), x in [bx, bx+16), all 32 channels
    for (int i = tid; i < 16 * 16 * 32; i += 256) {
        int c  = i & 31;
        int ix = (i >> 5) & 15;
        int iy = i >> 9;
        patch[i] = vbase[((by + iy) * WW + (bx + ix)) * CC + c];
    }
    __syncthreads();

    // 64 pixels x 25 oc-quads = 1600 items
    for (int u = tid; u < 1600; u += 256) {
        int q  = u % 25;
        int p  = u / 25;
        int oc = q * 4;
        int py_ = p >> 3, px_ = p & 7;
        float4 acc = *(const float4*)&b_off[oc];
        for (int t = 0; t < 25; ++t) {
            int fh = t / 5, fw = t % 5;
            const float* pp = &patch[((py_ + fh * 2) * 16 + (px_ + fw * 2)) * 32];
            const float* wp = &w_off[t * 32 * OFFC + oc];
            #pragma unroll
            for (int c = 0; c < 32; ++c) {
                float  pv = pp[c];
                float4 wv = *(const float4*)&wp[c * OFFC];
                acc.x = fmaf(pv, wv.x, acc.x);
                acc.y = fmaf(pv, wv.y, acc.y);
                acc.z = fmaf(pv, wv.z, acc.z);
                acc.w = fmaf(pv, wv.w, acc.w);
            }
        }
        *(float4*)&offs[(((size_t)b * OH + by + py_) * OW + bx + px_) * OFFC + oc] = acc;
    }
}

// ---------------------------------------------------------------------------
// Kernel 2: bilinear gather + grouped einsum.
// Block = 4 consecutive output pixels (flat over b,oy,ox), 256 threads.
// Phase A: sampled[4][25][2][32] -> LDS (25.6 KB). unit = (p,k,g,c-quad).
// Phase B: thread = p*64+f; sampled reads broadcast, w_dcn coalesced.
// ---------------------------------------------------------------------------
__global__ __launch_bounds__(256) void dcn_kernel(
    const float* __restrict__ volume, const float* __restrict__ offs,
    const float* __restrict__ w_dcn, const float* __restrict__ b_dcn,
    float* __restrict__ out)
{
    __shared__ float samp[4 * KT * GG * CC];   // 6400 floats
    const int tid = threadIdx.x;
    const long pbase = (long)blockIdx.x * 4;

    // Phase A: 200 (p,k,g) items x 8 c-quads = 1600 units
    for (int u = tid; u < 1600; u += 256) {
        int c4 = u & 7;
        int it = u >> 3;
        int g  = it & 1;
        int k  = (it >> 1) % 25;
        int p  = it / 50;
        long pix = pbase + p;
        int ox = (int)(pix % OW);
        int oy = (int)((pix / OW) % OH);
        int b  = (int)(pix / (OW * OH));

        const float* orow = offs + pix * OFFC + k * 4 + g;
        float dy = orow[0];
        float dx = orow[2];
        float py = (float)(oy + 2 * (k / 5)) + dy;
        float px = (float)(ox + 2 * (k % 5)) + dx;
        py = fminf(fmaxf(py, 0.f), (float)(HH - 1));
        px = fminf(fmaxf(px, 0.f), (float)(WW - 1));
        float y0f = fminf(fmaxf(floorf(py), 0.f), (float)(HH - 2));
        float x0f = fminf(fmaxf(floorf(px), 0.f), (float)(WW - 2));
        float wy = py - y0f, wx = px - x0f;
        int y0 = (int)y0f, x0 = (int)x0f;

        const float* v00 = volume + (((size_t)b * HH + y0) * WW + x0) * CC;
        float w00 = (1.f - wy) * (1.f - wx);
        float w01 = (1.f - wy) * wx;
        float w10 = wy * (1.f - wx);
        float w11 = wy * wx;

        const float4 q00 = *(const float4*)(v00 + c4 * 4);
        const float4 q01 = *(const float4*)(v00 + CC + c4 * 4);
        const float4 q10 = *(const float4*)(v00 + WW * CC + c4 * 4);
        const float4 q11 = *(const float4*)(v00 + WW * CC + CC + c4 * 4);
        float4 r;
        r.x = q00.x * w00 + q01.x * w01 + q10.x * w10 + q11.x * w11;
        r.y = q00.y * w00 + q01.y * w01 + q10.y * w10 + q11.y * w11;
        r.z = q00.z * w00 + q01.z * w01 + q10.z * w10 + q11.z * w11;
        r.w = q00.w * w00 + q01.w * w01 + q10.w * w11 * 0.f + q11.w * w11 + q10.w * w10; // placeholder fixed below
        // (correct w-lane written explicitly to avoid typo risk:)
        r.w = q00.w * w00 + q01.w * w01 + q10.w * w10 + q11.w * w11;
        *(float4*)&samp[it * 32 + c4 * 4] = r;
    }
    __syncthreads();

    // Phase B: einsum out[p, f] = b + sum_{k,c} samp[p,k,g,c] * w_dcn[k,c,f]
    int f = tid & 63;
    int p = tid >> 6;
    int g = f >> 5;
    float acc = b_dcn[f];
    const float* sbase = &samp[(p * 50 + g) * 32];
    for (int k = 0; k < 25; ++k) {
        const float* s  = sbase + k * 64;
        const float* wk = w_dcn + k * 32 * 64 + f;
        #pragma unroll
        for (int c = 0; c < 32; ++c)
            acc = fmaf(s[c], wk[c * 64], acc);
    }
    long pix = pbase + p;
    out[pix * 64 + f] = acc;
}

extern "C" void kernel_launch(void* const* d_in, const int* in_sizes, int n_in,
                              void* d_out, int out_size, void* d_ws, size_t ws_size,
                              hipStream_t stream) {
    const float* volume = (const float*)d_in[0];
    const float* w_off  = (const float*)d_in[1];
    const float* b_off  = (const float*)d_in[2];
    const float* w_dcn  = (const float*)d_in[3];
    const float* b_dcn  = (const float*)d_in[4];
    float* out  = (float*)d_out;
    float* offs = (float*)d_ws;   // needs 4*120*120*100*4 = 23.04 MB

    dim3 g1(OW / 8, OH / 8, BB);  // 15 x 15 x 4
    offsets_kernel<<<g1, 256, 0, stream>>>(volume, w_off, b_off, offs);

    int nblk = (BB * OH * OW) / 4;  // 14400
    dcn_kernel<<<nblk, 256, 0, stream>>>(volume, offs, w_dcn, b_dcn, out);
}

// Round 2
// 255.613 us; speedup vs baseline: 4.2020x; 4.2020x over previous
//
#include <hip/hip_runtime.h>
#include <hip/hip_bf16.h>

#define BB 4
#define HH 128
#define WW 128
#define CC 32
#define OH 120
#define OW 120
#define KT 25
#define OFFC 100
#define FF 64

typedef __attribute__((ext_vector_type(8))) short bf16x8;
typedef __attribute__((ext_vector_type(4))) float f32x4;

// d_ws layout (bf16 elements):
//   offs:  [BB*OH*OW][OFFC]                 5,760,000 elems
//   WB:    [25 taps][7 n-tiles][64 lane][8] 89,600
//   WD:    [4 n-tiles][25 taps][64 lane][8] 51,200
#define OFFS_ELEMS (BB * OH * OW * OFFC)
#define WB_ELEMS   (KT * 7 * 64 * 8)
#define WD_ELEMS   (4 * KT * 64 * 8)

__device__ __forceinline__ short f2bf(float x) {
    __hip_bfloat16 h = __float2bfloat16(x);
    return *reinterpret_cast<short*>(&h);
}
__device__ __forceinline__ float bf2f(short x) {
    __hip_bfloat16 h = *reinterpret_cast<__hip_bfloat16*>(&x);
    return __bfloat162float(h);
}

// ---------------------------------------------------------------------------
// Repack weights into B-fragment layout for mfma_f32_16x16x32_bf16:
//   B[k=c][col]: lane l holds col=l&15, k-chunk c=(l>>4)*8+j, j=0..7
// ---------------------------------------------------------------------------
__global__ __launch_bounds__(256) void repack_kernel(
    const float* __restrict__ w_off, const float* __restrict__ w_dcn,
    short* __restrict__ ws)
{
    int idx = blockIdx.x * 256 + threadIdx.x;
    short* WB = ws + OFFS_ELEMS;
    short* WD = WB + WB_ELEMS;
    if (idx < WB_ELEMS) {
        int j = idx & 7, l = (idx >> 3) & 63;
        int tn = idx >> 9;            // t*7 + n
        int n = tn % 7, t = tn / 7;
        int c = (l >> 4) * 8 + j;
        int oc = n * 16 + (l & 15);
        float v = (oc < OFFC) ? w_off[(t * CC + c) * OFFC + oc] : 0.f;
        WB[idx] = f2bf(v);
    }
    int idx2 = idx - WB_ELEMS;
    if (idx2 >= 0 && idx2 < WD_ELEMS) {
        int j = idx2 & 7, l = (idx2 >> 3) & 63;
        int nt = idx2 >> 9;           // n*25 + t
        int t = nt % KT, n = nt / KT;
        int c = (l >> 4) * 8 + j;
        int f = n * 16 + (l & 15);
        WD[idx2] = f2bf(w_dcn[(t * CC + c) * FF + f]);
    }
}

// ---------------------------------------------------------------------------
// Kernel 1: offset conv as MFMA GEMM. Block = 8x8 output pixels, 4 waves.
// M = 64 px (wave w owns M-tile w), N = 112 (7 tiles, oc>=100 masked), K = 800.
// Patch 16x16x32 bf16 in LDS, 16B-unit addr swizzled with ((ix>>1)&3).
// ---------------------------------------------------------------------------
__global__ __launch_bounds__(256) void offsets_mfma(
    const float* __restrict__ volume, const short* __restrict__ ws,
    const float* __restrict__ b_off, short* __restrict__ offs)
{
    __shared__ short patch[16 * 16 * 32];   // 16 KB
    const short* WB = ws + OFFS_ELEMS;
    const int tid = threadIdx.x;
    const int lane = tid & 63;
    const int wv = tid >> 6;
    const int bx = blockIdx.x * 8, by = blockIdx.y * 8, b = blockIdx.z;
    const float* vbase = volume + (size_t)b * HH * WW * CC;

    // stage 16x16x32 fp32 -> bf16 LDS (swizzled)
    for (int u = tid; u < 1024; u += 256) {
        int cq = u & 3, ix = (u >> 2) & 15, iy = u >> 6;
        const float* src = vbase + ((size_t)(by + iy) * WW + (bx + ix)) * CC + cq * 8;
        float4 q0 = *(const float4*)src;
        float4 q1 = *(const float4*)(src + 4);
        alignas(16) short tmp[8];
        tmp[0] = f2bf(q0.x); tmp[1] = f2bf(q0.y); tmp[2] = f2bf(q0.z); tmp[3] = f2bf(q0.w);
        tmp[4] = f2bf(q1.x); tmp[5] = f2bf(q1.y); tmp[6] = f2bf(q1.z); tmp[7] = f2bf(q1.w);
        int a16 = (iy * 64 + ix * 4 + cq) ^ ((ix >> 1) & 3);
        *(bf16x8*)&patch[a16 * 8] = *(const bf16x8*)tmp;
    }
    __syncthreads();

    f32x4 acc[7];
    #pragma unroll
    for (int n = 0; n < 7; ++n) acc[n] = (f32x4){0.f, 0.f, 0.f, 0.f};

    const int p  = wv * 16 + (lane & 15);
    const int py = p >> 3, px = p & 7;
    const int cq = lane >> 4;

    for (int t = 0; t < KT; ++t) {
        int fh = t / 5, fw = t % 5;
        int iy = py + 2 * fh, ix = px + 2 * fw;
        int a16 = (iy * 64 + ix * 4 + cq) ^ ((ix >> 1) & 3);
        bf16x8 afrag = *(const bf16x8*)&patch[a16 * 8];
        const short* wb = WB + t * 7 * 512 + lane * 8;
        #pragma unroll
        for (int n = 0; n < 7; ++n) {
            bf16x8 bfrag = *(const bf16x8*)(wb + n * 512);
            acc[n] = __builtin_amdgcn_mfma_f32_16x16x32_bf16(afrag, bfrag, acc[n], 0, 0, 0);
        }
    }

    // epilogue: C/D layout col=lane&15, row=(lane>>4)*4+r (HW-verified)
    const int col = lane & 15;
    const int r0 = (lane >> 4) * 4;
    for (int n = 0; n < 7; ++n) {
        int oc = n * 16 + col;
        if (oc >= OFFC) continue;
        float bo = b_off[oc];
        #pragma unroll
        for (int r = 0; r < 4; ++r) {
            int pp = wv * 16 + r0 + r;
            int ppy = pp >> 3, ppx = pp & 7;
            size_t oi = (((size_t)b * OH + by + ppy) * OW + (bx + ppx)) * OFFC + oc;
            offs[oi] = f2bf(acc[n][r] + bo);
        }
    }
}

// ---------------------------------------------------------------------------
// Kernel 2: bilinear gather (bf16 -> swizzled LDS) + MFMA einsum.
// Block = 16 pixels, 4 waves; wave w computes f-tile w (g = w>>1). K = 800.
// ---------------------------------------------------------------------------
__global__ __launch_bounds__(256) void dcn_mfma(
    const float* __restrict__ volume, const short* __restrict__ ws,
    const float* __restrict__ b_dcn, float* __restrict__ out)
{
    __shared__ short samp[16 * KT * 2 * CC];   // 50 KB
    const short* offs = ws;
    const short* WD = ws + OFFS_ELEMS + WB_ELEMS;
    const int tid = threadIdx.x;
    const long pbase = (long)blockIdx.x * 16;

    for (int u = tid; u < 800; u += 256) {
        int g = u & 1, t = (u >> 1) % KT, p = u / 50;
        long pix = pbase + p;
        int ox = (int)(pix % OW);
        int oy = (int)((pix / OW) % OH);
        int b  = (int)(pix / ((long)OW * OH));
        float dy = bf2f(offs[pix * OFFC + t * 4 + g]);
        float dx = bf2f(offs[pix * OFFC + t * 4 + 2 + g]);
        float py = (float)(oy + 2 * (t / 5)) + dy;
        float px = (float)(ox + 2 * (t % 5)) + dx;
        py = fminf(fmaxf(py, 0.f), 127.f);
        px = fminf(fmaxf(px, 0.f), 127.f);
        float y0f = fminf(fmaxf(floorf(py), 0.f), 126.f);
        float x0f = fminf(fmaxf(floorf(px), 0.f), 126.f);
        float wy = py - y0f, wx = px - x0f;
        int y0 = (int)y0f, x0 = (int)x0f;
        const float* v00 = volume + (((size_t)b * HH + y0) * WW + x0) * CC;
        float w00 = (1.f - wy) * (1.f - wx);
        float w01 = (1.f - wy) * wx;
        float w10 = wy * (1.f - wx);
        float w11 = wy * wx;
        int base16 = p * 200 + t * 8 + g * 4;
        int sw = p & 7;
        #pragma unroll
        for (int cq = 0; cq < 4; ++cq) {
            float4 a0 = *(const float4*)(v00 + cq * 8);
            float4 a1 = *(const float4*)(v00 + cq * 8 + 4);
            float4 b0 = *(const float4*)(v00 + CC + cq * 8);
            float4 b1 = *(const float4*)(v00 + CC + cq * 8 + 4);
            float4 c0 = *(const float4*)(v00 + WW * CC + cq * 8);
            float4 c1 = *(const float4*)(v00 + WW * CC + cq * 8 + 4);
            float4 d0 = *(const float4*)(v00 + WW * CC + CC + cq * 8);
            float4 d1 = *(const float4*)(v00 + WW * CC + CC + cq * 8 + 4);
            alignas(16) short tmp[8];
            tmp[0] = f2bf(a0.x * w00 + b0.x * w01 + c0.x * w10 + d0.x * w11);
            tmp[1] = f2bf(a0.y * w00 + b0.y * w01 + c0.y * w10 + d0.y * w11);
            tmp[2] = f2bf(a0.z * w00 + b0.z * w01 + c0.z * w10 + d0.z * w11);
            tmp[3] = f2bf(a0.w * w00 + b0.w * w01 + c0.w * w10 + d0.w * w11);
            tmp[4] = f2bf(a1.x * w00 + b1.x * w01 + c1.x * w10 + d1.x * w11);
            tmp[5] = f2bf(a1.y * w00 + b1.y * w01 + c1.y * w10 + d1.y * w11);
            tmp[6] = f2bf(a1.z * w00 + b1.z * w01 + c1.z * w10 + d1.z * w11);
            tmp[7] = f2bf(a1.w * w00 + b1.w * w01 + c1.w * w10 + d1.w * w11);
            *(bf16x8*)&samp[((base16 + cq) ^ sw) * 8] = *(const bf16x8*)tmp;
        }
    }
    __syncthreads();

    const int lane = tid & 63, wv = tid >> 6;
    const int g = wv >> 1;
    f32x4 acc = (f32x4){0.f, 0.f, 0.f, 0.f};
    const int p = lane & 15, cq = lane >> 4;
    const int abase = p * 200 + g * 4 + cq;
    const int sw = p & 7;
    const short* wd = WD + wv * KT * 512 + lane * 8;
    for (int t = 0; t < KT; ++t) {
        bf16x8 afrag = *(const bf16x8*)&samp[((abase + t * 8) ^ sw) * 8];
        bf16x8 bfrag = *(const bf16x8*)(wd + t * 512);
        acc = __builtin_amdgcn_mfma_f32_16x16x32_bf16(afrag, bfrag, acc, 0, 0, 0);
    }
    const int f = wv * 16 + (lane & 15);
    float bd = b_dcn[f];
    #pragma unroll
    for (int r = 0; r < 4; ++r) {
        int pp = (lane >> 4) * 4 + r;
        out[(pbase + pp) * FF + f] = acc[r] + bd;
    }
}

extern "C" void kernel_launch(void* const* d_in, const int* in_sizes, int n_in,
                              void* d_out, int out_size, void* d_ws, size_t ws_size,
                              hipStream_t stream) {
    const float* volume = (const float*)d_in[0];
    const float* w_off  = (const float*)d_in[1];
    const float* b_off  = (const float*)d_in[2];
    const float* w_dcn  = (const float*)d_in[3];
    const float* b_dcn  = (const float*)d_in[4];
    float* out = (float*)d_out;
    short* ws  = (short*)d_ws;   // ~11.8 MB of bf16

    int repack_blocks = (WB_ELEMS + WD_ELEMS) / 256;   // 550
    repack_kernel<<<repack_blocks, 256, 0, stream>>>(w_off, w_dcn, ws);

    dim3 g1(OW / 8, OH / 8, BB);  // 15 x 15 x 4
    offsets_mfma<<<g1, 256, 0, stream>>>(volume, ws, b_off, ws);

    int nblk = (BB * OH * OW) / 16;  // 3600
    dcn_mfma<<<nblk, 256, 0, stream>>>(volume, ws, b_dcn, out);
}

// Round 3
// 169.569 us; speedup vs baseline: 6.3343x; 1.5074x over previous
//
#include <hip/hip_runtime.h>
#include <hip/hip_bf16.h>

#define BB 4
#define HH 128
#define WW 128
#define CC 32
#define OH 120
#define OW 120
#define KT 25
#define OFFC 100
#define FF 64

typedef __attribute__((ext_vector_type(8))) short bf16x8;
typedef __attribute__((ext_vector_type(4))) float f32x4;

// d_ws layout (bf16/short elements):
//   offs:  [BB*OH*OW][OFFC]                    5,760,000
//   WB:    [25 taps][7 n][64 lane][8]             89,600
//   WD:    [4 n][25 taps][64 lane][8]             51,200
//   V16:   bf16 copy of volume [B][H][W][C]    2,097,152
#define OFFS_ELEMS (BB * OH * OW * OFFC)
#define WB_ELEMS   (KT * 7 * 64 * 8)
#define WD_ELEMS   (4 * KT * 64 * 8)
#define VOL_UNITS  (BB * HH * WW * CC / 8)   // 262,144 bf16x8 units
#define VOL16_OFF  (OFFS_ELEMS + WB_ELEMS + WD_ELEMS)

__device__ __forceinline__ short f2bf(float x) {
    __hip_bfloat16 h = __float2bfloat16(x);
    return *reinterpret_cast<short*>(&h);
}
__device__ __forceinline__ float bf2f(short x) {
    __hip_bfloat16 h = *reinterpret_cast<__hip_bfloat16*>(&x);
    return __bfloat162float(h);
}

// ---------------------------------------------------------------------------
// Repack: weights -> MFMA B-fragment layout; volume fp32 -> bf16.
// ---------------------------------------------------------------------------
__global__ __launch_bounds__(256) void repack_kernel(
    const float* __restrict__ volume, const float* __restrict__ w_off,
    const float* __restrict__ w_dcn, short* __restrict__ ws)
{
    int idx = blockIdx.x * 256 + threadIdx.x;
    short* WB  = ws + OFFS_ELEMS;
    short* WD  = WB + WB_ELEMS;
    short* V16 = ws + VOL16_OFF;
    if (idx < WB_ELEMS) {
        int j = idx & 7, l = (idx >> 3) & 63;
        int tn = idx >> 9;            // t*7 + n
        int n = tn % 7, t = tn / 7;
        int c = (l >> 4) * 8 + j;
        int oc = n * 16 + (l & 15);
        float v = (oc < OFFC) ? w_off[(t * CC + c) * OFFC + oc] : 0.f;
        WB[idx] = f2bf(v);
    } else if (idx < WB_ELEMS + WD_ELEMS) {
        int idx2 = idx - WB_ELEMS;
        int j = idx2 & 7, l = (idx2 >> 3) & 63;
        int nt = idx2 >> 9;           // n*25 + t
        int t = nt % KT, n = nt / KT;
        int c = (l >> 4) * 8 + j;
        int f = n * 16 + (l & 15);
        WD[idx2] = f2bf(w_dcn[(t * CC + c) * FF + f]);
    } else {
        int v = idx - (WB_ELEMS + WD_ELEMS);
        if (v < VOL_UNITS) {
            const float* src = volume + (size_t)v * 8;
            float4 q0 = *(const float4*)src;
            float4 q1 = *(const float4*)(src + 4);
            alignas(16) short tmp[8];
            tmp[0] = f2bf(q0.x); tmp[1] = f2bf(q0.y); tmp[2] = f2bf(q0.z); tmp[3] = f2bf(q0.w);
            tmp[4] = f2bf(q1.x); tmp[5] = f2bf(q1.y); tmp[6] = f2bf(q1.z); tmp[7] = f2bf(q1.w);
            *(bf16x8*)&V16[(size_t)v * 8] = *(const bf16x8*)tmp;
        }
    }
}

// ---------------------------------------------------------------------------
// Kernel 1: offset conv as MFMA GEMM. 8x8 px tile, 4 waves, M=64, N=112, K=800.
// B-fragments staged per filter-row chunk (5 taps, 35 KB) in LDS, shared by
// all 4 waves; A-patch 16x16x32 bf16 in swizzled LDS.
// ---------------------------------------------------------------------------
__global__ __launch_bounds__(256) void offsets_mfma(
    const short* __restrict__ ws_ro, const float* __restrict__ b_off,
    short* __restrict__ offs_out)
{
    __shared__ short patch[16 * 16 * 32];   // 16 KB
    __shared__ short Bbuf[5 * 7 * 64 * 8];  // 35 KB (one 5-tap chunk)
    const short* V16 = ws_ro + VOL16_OFF;
    const short* WB  = ws_ro + OFFS_ELEMS;
    const int tid = threadIdx.x;
    const int lane = tid & 63;
    const int wv = tid >> 6;
    const int bx = blockIdx.x * 8, by = blockIdx.y * 8, b = blockIdx.z;

    // stage A patch (bf16 source, swizzled dest)
    for (int u = tid; u < 1024; u += 256) {
        int cq = u & 3, ix = (u >> 2) & 15, iy = u >> 6;
        bf16x8 val = *(const bf16x8*)&V16[(((size_t)(b * HH + by + iy)) * WW + (bx + ix)) * CC + cq * 8];
        *(bf16x8*)&patch[((iy * 64 + ix * 4 + cq) ^ ((ix >> 1) & 3)) * 8] = val;
    }
    // stage B chunk 0
    for (int i = tid; i < 2240; i += 256)
        *(bf16x8*)&Bbuf[i * 8] = *(const bf16x8*)&WB[i * 8];
    __syncthreads();

    f32x4 acc[7];
    #pragma unroll
    for (int n = 0; n < 7; ++n) acc[n] = (f32x4){0.f, 0.f, 0.f, 0.f};

    const int p  = wv * 16 + (lane & 15);
    const int py = p >> 3, px = p & 7;
    const int cq = lane >> 4;

    for (int c = 0; c < 5; ++c) {          // chunk = filter row fh
        #pragma unroll
        for (int tl = 0; tl < 5; ++tl) {   // fw
            int iy = py + 2 * c, ix = px + 2 * tl;
            bf16x8 af = *(const bf16x8*)&patch[((iy * 64 + ix * 4 + cq) ^ ((ix >> 1) & 3)) * 8];
            const short* bb = &Bbuf[(tl * 7) * 512 + lane * 8];
            #pragma unroll
            for (int n = 0; n < 7; ++n) {
                bf16x8 bf = *(const bf16x8*)&bb[n * 512];
                acc[n] = __builtin_amdgcn_mfma_f32_16x16x32_bf16(af, bf, acc[n], 0, 0, 0);
            }
        }
        if (c < 4) {
            __syncthreads();
            const short* src = &WB[(c + 1) * 17920];
            for (int i = tid; i < 2240; i += 256)
                *(bf16x8*)&Bbuf[i * 8] = *(const bf16x8*)&src[i * 8];
            __syncthreads();
        }
    }

    // epilogue: C/D layout col=lane&15, row=(lane>>4)*4+r
    const int col = lane & 15;
    const int r0 = (lane >> 4) * 4;
    for (int n = 0; n < 7; ++n) {
        int oc = n * 16 + col;
        if (oc >= OFFC) continue;
        float bo = b_off[oc];
        #pragma unroll
        for (int r = 0; r < 4; ++r) {
            int pp = wv * 16 + r0 + r;
            int ppy = pp >> 3, ppx = pp & 7;
            size_t oi = (((size_t)b * OH + by + ppy) * OW + (bx + ppx)) * OFFC + oc;
            offs_out[oi] = f2bf(acc[n][r] + bo);
        }
    }
}

// ---------------------------------------------------------------------------
// Kernel 2: coalesced bilinear gather (bf16 volume) + MFMA einsum.
// Block = 16 px of one output row, 4 waves. Gather unit = (item, c8):
// 4 lanes/item, each loads bf16x8 per corner (64B contiguous per corner pair).
// ---------------------------------------------------------------------------
__global__ __launch_bounds__(256) void dcn_mfma(
    const short* __restrict__ ws_ro, const float* __restrict__ b_dcn,
    float* __restrict__ out)
{
    __shared__ short samp[16 * KT * 2 * CC];   // 50 KB
    const short* offs = ws_ro;
    const short* WD   = ws_ro + OFFS_ELEMS + WB_ELEMS;
    const short* V16  = ws_ro + VOL16_OFF;
    const int tid = threadIdx.x;
    const int bx = blockIdx.x, oy = blockIdx.y, b = blockIdx.z;
    const int pix0 = (b * OH + oy) * OW + bx * 16;

    for (int u = tid; u < 3200; u += 256) {
        int c8 = u & 3;
        int item = u >> 2;                       // [0,800)
        int p = (int)((unsigned)item / 50u);
        int r = item - p * 50;
        int t = r >> 1, g = r & 1;
        int ox = bx * 16 + p;
        int pe = (ox < OW) ? p : (OW - 1 - bx * 16);
        int pix = pix0 + pe;
        float dy = bf2f(offs[(size_t)pix * OFFC + t * 4 + g]);
        float dx = bf2f(offs[(size_t)pix * OFFC + t * 4 + 2 + g]);
        int t5 = (int)((unsigned)t / 5u);
        int tm5 = t - t5 * 5;
        float py = (float)(oy + 2 * t5) + dy;
        float px = (float)(bx * 16 + pe + 2 * tm5) + dx;
        py = fminf(fmaxf(py, 0.f), 127.f);
        px = fminf(fmaxf(px, 0.f), 127.f);
        float y0f = fminf(floorf(py), 126.f);
        float x0f = fminf(floorf(px), 126.f);
        float wy = py - y0f, wx = px - x0f;
        int y0 = (int)y0f, x0 = (int)x0f;
        float w00 = (1.f - wy) * (1.f - wx);
        float w01 = (1.f - wy) * wx;
        float w10 = wy * (1.f - wx);
        float w11 = wy * wx;
        const short* vb = V16 + (((size_t)(b * HH + y0)) * WW + x0) * CC + c8 * 8;
        bf16x8 Av = *(const bf16x8*)vb;
        bf16x8 Bv = *(const bf16x8*)(vb + CC);
        bf16x8 Cv = *(const bf16x8*)(vb + WW * CC);
        bf16x8 Dv = *(const bf16x8*)(vb + WW * CC + CC);
        alignas(16) short tmp[8];
        #pragma unroll
        for (int j = 0; j < 8; ++j) {
            float vv = bf2f(Av[j]) * w00 + bf2f(Bv[j]) * w01
                     + bf2f(Cv[j]) * w10 + bf2f(Dv[j]) * w11;
            tmp[j] = f2bf(vv);
        }
        *(bf16x8*)&samp[((p * 200 + t * 8 + g * 4 + c8) ^ (p & 7)) * 8] = *(const bf16x8*)tmp;
    }
    __syncthreads();

    const int lane = tid & 63, wv = tid >> 6;
    const int g = wv >> 1;
    f32x4 acc = (f32x4){0.f, 0.f, 0.f, 0.f};
    const int p = lane & 15, cq = lane >> 4;
    const int abase = p * 200 + g * 4 + cq;
    const int sw = p & 7;
    const short* wd = WD + wv * KT * 512 + lane * 8;
    for (int t = 0; t < KT; ++t) {
        bf16x8 af = *(const bf16x8*)&samp[((abase + t * 8) ^ sw) * 8];
        bf16x8 bf = *(const bf16x8*)&wd[t * 512];
        acc = __builtin_amdgcn_mfma_f32_16x16x32_bf16(af, bf, acc, 0, 0, 0);
    }
    const int f = wv * 16 + (lane & 15);
    const float bd = b_dcn[f];
    #pragma unroll
    for (int rr = 0; rr < 4; ++rr) {
        int pp = (lane >> 4) * 4 + rr;
        if (bx * 16 + pp < OW)
            out[((size_t)(pix0 + pp)) * FF + f] = acc[rr] + bd;
    }
}

extern "C" void kernel_launch(void* const* d_in, const int* in_sizes, int n_in,
                              void* d_out, int out_size, void* d_ws, size_t ws_size,
                              hipStream_t stream) {
    const float* volume = (const float*)d_in[0];
    const float* w_off  = (const float*)d_in[1];
    const float* b_off  = (const float*)d_in[2];
    const float* w_dcn  = (const float*)d_in[3];
    const float* b_dcn  = (const float*)d_in[4];
    float* out = (float*)d_out;
    short* ws  = (short*)d_ws;   // 16.0 MB of bf16 used

    int repack_blocks = (WB_ELEMS + WD_ELEMS + VOL_UNITS + 255) / 256;  // 1574
    repack_kernel<<<repack_blocks, 256, 0, stream>>>(volume, w_off, w_dcn, ws);

    dim3 g1(OW / 8, OH / 8, BB);  // 15 x 15 x 4
    offsets_mfma<<<g1, 256, 0, stream>>>(ws, b_off, ws);

    dim3 g2((OW + 15) / 16, OH, BB);  // 8 x 120 x 4
    dcn_mfma<<<g2, 256, 0, stream>>>(ws, b_dcn, out);
}